// Round 7
// baseline (553.049 us; speedup 1.0000x reference)
//
#include <hip/hip_runtime.h>
#include <hip/hip_bf16.h>
#include <cstdint>
#include <cstddef>

// ---------------------------------------------------------------------------
// SelfAttentionV1: out = softmax((x Wq^T)(x Wk^T)^T / 32) (x Wv^T)
// N=8192, D=1024. Round 6 (resubmit after GPU-acquisition timeout):
// occupancy play. 128x128 tile, 4-wave blocks, ring-2 LDS (32 KiB) -> 4
// independent blocks/CU. One vmcnt(0)+barrier per BK=32 tile (m97
// semantics); cross-block TLP absorbs the drain.
// ---------------------------------------------------------------------------

typedef __attribute__((ext_vector_type(8))) short short8;     // bf16x8 MFMA frag
typedef __attribute__((ext_vector_type(8))) unsigned short ushort8;
typedef __attribute__((ext_vector_type(4))) float f32x4;

#define FENCE asm volatile("" ::: "memory")

__device__ __forceinline__ unsigned short f2bf(float f) {
  unsigned u = __float_as_uint(f);
  u += 0x7fffu + ((u >> 16) & 1u);      // round-to-nearest-even
  return (unsigned short)(u >> 16);
}
__device__ __forceinline__ float bf2f(unsigned short h) {
  return __uint_as_float(((unsigned)h) << 16);
}

// async global->LDS, 16 bytes per lane (wave-uniform LDS base + lane*16)
__device__ __forceinline__ void glds16(const void* g, void* l) {
  __builtin_amdgcn_global_load_lds((__attribute__((address_space(1))) void*)g,
                                   (__attribute__((address_space(3))) void*)l,
                                   16, 0, 0);
}

// ---- fp32 -> bf16 cast, 8 elems/thread ----
__global__ __launch_bounds__(256) void cast_kernel(const float* __restrict__ in,
                                                   unsigned short* __restrict__ out,
                                                   int n8) {
  int i = blockIdx.x * 256 + threadIdx.x;
  if (i >= n8) return;
  const f32x4* in4 = (const f32x4*)in;
  f32x4 a = in4[2 * i];
  f32x4 b = in4[2 * i + 1];
  ushort8 o;
#pragma unroll
  for (int j = 0; j < 4; ++j) o[j] = f2bf(a[j]);
#pragma unroll
  for (int j = 0; j < 4; ++j) o[4 + j] = f2bf(b[j]);
  ((ushort8*)out)[i] = o;
}

// ---------------------------------------------------------------------------
// GEMM core: C[gm0..+128, gn0..+128] = scale * A * B^T  (A,B bf16 [*, K] rows)
// 256 thr = 4 waves (2M x 2N), wave-out 64x64 (4x4 frags of 16x16x32).
// BK=32, ring-2 LDS slots (2 x 16 KiB), distance-1 prefetch, ONE barrier/tile
// with vmcnt(0) drain (4 blocks/CU cover each other's drain windows).
// LDS slot: A plane [128 rows][64 B] at 0, B plane at 8192.
// Swizzle (r2-verified, 0 conflicts): colbyte ^= ((row>>1)&3)<<4; staging
// pre-swizzles the GLOBAL source, LDS dest linear (rule #21).
// ---------------------------------------------------------------------------
#define MFMA_OP(mi, ni, av, bv) \
  acc[mi][ni] = __builtin_amdgcn_mfma_f32_16x16x32_bf16(av, bv, acc[mi][ni], 0, 0, 0)

template <typename OutT>
__device__ __forceinline__ void gemm_core(
    const unsigned short* __restrict__ A, const unsigned short* __restrict__ B,
    OutT* __restrict__ C, int ldc, size_t ldab /*row bytes*/, int NT,
    int gm0, int gn0, float scale, char* lds) {
  const int tid = threadIdx.x;
  const int lane = tid & 63;
  const int wm = (tid >> 7) & 1, wn = (tid >> 6) & 1;   // wave 2x2

  // ---- staging (writer): inst covers 64 rows; thread t -> row (t>>2),
  // 16B slot (t&3). Source col pre-swizzled by ((row>>1)&3)<<4 =
  // ((t>>3)&3)<<4 (lane-constant). LDS dest linear: slotbase + t*16.
  const int srow = tid >> 2;
  const int scol = ((tid & 3) << 4) ^ (((tid >> 3) & 3) << 4);
  const char* pA0 = (const char*)A + (size_t)(gm0 + srow) * ldab + scol;
  const char* pA1 = pA0 + (size_t)64 * ldab;
  const char* pB0 = (const char*)B + (size_t)(gn0 + srow) * ldab + scol;
  const char* pB1 = pB0 + (size_t)64 * ldab;
  const int dst = tid * 16;   // + region offset {0,4096,8192,12288} + slot*16384

  // ---- reader: frag row = wq*64 + mi*16 + (lane&15), col (lane>>4)*16 B,
  // swizzle term reduces to ((lane>>1)&3)<<4 (bases multiples of 16).
  const int colb = ((lane >> 4) << 4) ^ (((lane >> 1) & 3) << 4);
  const int aoff = (wm * 64 + (lane & 15)) * 64 + colb;
  const int boff = (wn * 64 + (lane & 15)) * 64 + colb + 8192;

  f32x4 acc[4][4];
#pragma unroll
  for (int m = 0; m < 4; ++m)
#pragma unroll
    for (int n = 0; n < 4; ++n) acc[m][n] = (f32x4)(0.0f);

  // ---- prologue: stage tile 0 into slot 0, drain, barrier
  glds16(pA0, lds + dst);
  glds16(pA1, lds + 4096 + dst);
  glds16(pB0, lds + 8192 + dst);
  glds16(pB1, lds + 12288 + dst);
  asm volatile("s_waitcnt vmcnt(0)" ::: "memory");
  __builtin_amdgcn_s_barrier();
  FENCE;

  const char* sA0 = pA0 + 64;   // tile t+1 sources (K advances 64 B)
  const char* sA1 = pA1 + 64;
  const char* sB0 = pB0 + 64;
  const char* sB1 = pB1 + 64;

#pragma unroll 2
  for (int t = 0; t < NT; ++t) {
    const char* Ls = lds + (t & 1) * 16384;
    char* Ld = lds + ((t + 1) & 1) * 16384;
    const bool stg = (t + 1 < NT);

    // issue next-tile staging first (latency hides under MFMA + other blocks)
    if (stg) {
      glds16(sA0, Ld + dst);
      glds16(sA1, Ld + 4096 + dst);
      glds16(sB0, Ld + 8192 + dst);
      glds16(sB1, Ld + 12288 + dst);
      sA0 += 64; sA1 += 64; sB0 += 64; sB1 += 64;
    }

    short8 aF[4], bF[4];
#pragma unroll
    for (int m = 0; m < 4; ++m)
      aF[m] = *(const short8*)(Ls + aoff + m * 1024);
#pragma unroll
    for (int n = 0; n < 4; ++n)
      bF[n] = *(const short8*)(Ls + boff + n * 1024);

    __builtin_amdgcn_s_setprio(1);
#pragma unroll
    for (int m = 0; m < 4; ++m) {
      MFMA_OP(m, 0, aF[m], bF[0]); MFMA_OP(m, 1, aF[m], bF[1]);
      MFMA_OP(m, 2, aF[m], bF[2]); MFMA_OP(m, 3, aF[m], bF[3]);
    }
    __builtin_amdgcn_s_setprio(0);

    // boundary: next tile fully landed, then all waves cross together
    asm volatile("s_waitcnt vmcnt(0)" ::: "memory");
    __builtin_amdgcn_s_barrier();
    FENCE;
  }

  // ---- epilogue: C row=(lane>>4)*4+j, col=lane&15 (m89-verified layout)
  const int r0 = gm0 + wm * 64 + ((lane >> 4) << 2);
  const int c0 = gn0 + wn * 64 + (lane & 15);
#pragma unroll
  for (int mi = 0; mi < 4; ++mi) {
#pragma unroll
    for (int ni = 0; ni < 4; ++ni) {
      f32x4 v = acc[mi][ni];
#pragma unroll
      for (int j = 0; j < 4; ++j) {
        float val = v[j] * scale;
        size_t idx = (size_t)(r0 + mi * 16 + j) * ldc + (c0 + ni * 16);
        if (sizeof(OutT) == 2) ((unsigned short*)C)[idx] = f2bf(val);
        else                   ((float*)C)[idx] = val;
      }
    }
  }
}

// bijective XCD chunking: consecutive logical blocks land on the same XCD
__device__ __forceinline__ void swz_block(int& bx, int& by, int& bz) {
  const int gx = gridDim.x, gy = gridDim.y;
  const int f = (blockIdx.z * gy + blockIdx.y) * gx + blockIdx.x;
  const int nwg = gx * gy * gridDim.z;      // all grids are multiples of 8
  const int q = nwg >> 3;
  const int l = (f & 7) * q + (f >> 3);
  bx = l % gx;
  const int r = l / gx;
  by = r % gy;
  bz = r / gy;
}

__global__ __launch_bounds__(256, 4) void gemm_s_kernel(
    const unsigned short* __restrict__ Q, const unsigned short* __restrict__ Kh,
    unsigned short* __restrict__ S) {
  __shared__ char lds[2 * 16384];
  int bx, by, bz; swz_block(bx, by, bz);
  gemm_core<unsigned short>(Q, Kh, S, 8192, 2048, 32, by * 128, bx * 128,
                            0.03125f, lds);
}

__global__ __launch_bounds__(256, 4) void gemm_qkv_kernel(
    const unsigned short* __restrict__ X,
    const unsigned short* __restrict__ Wq, const unsigned short* __restrict__ Wk,
    const unsigned short* __restrict__ Wv,
    unsigned short* __restrict__ Qo, unsigned short* __restrict__ Ko,
    unsigned short* __restrict__ Vo) {
  __shared__ char lds[2 * 16384];
  int bx, by, bz; swz_block(bx, by, bz);
  const unsigned short* B = (bz == 0) ? Wq : (bz == 1) ? Wk : Wv;
  unsigned short* C = (bz == 0) ? Qo : (bz == 1) ? Ko : Vo;
  gemm_core<unsigned short>(X, B, C, 1024, 2048, 32, by * 128, bx * 128,
                            1.0f, lds);
}

// PV with split-K x2: z=0 writes d_out, z=1 writes partial buffer
__global__ __launch_bounds__(256, 4) void gemm_pv_kernel(
    const unsigned short* __restrict__ S, const unsigned short* __restrict__ Vt,
    float* __restrict__ O, float* __restrict__ P1) {
  __shared__ char lds[2 * 16384];
  int bx, by, bz; swz_block(bx, by, bz);
  const unsigned short* A = S + (size_t)bz * 4096;   // k-offset 4096 elems
  const unsigned short* B = Vt + (size_t)bz * 4096;
  float* C = bz ? P1 : O;
  gemm_core<float>(A, B, C, 1024, 16384, 128, by * 128, bx * 128, 1.0f, lds);
}

__global__ __launch_bounds__(256) void add_kernel(float* __restrict__ out,
                                                  const float* __restrict__ p,
                                                  int n4) {
  int i = blockIdx.x * 256 + threadIdx.x;
  if (i < n4) {
    f32x4 a = ((const f32x4*)out)[i];
    f32x4 b = ((const f32x4*)p)[i];
    ((f32x4*)out)[i] = a + b;
  }
}

// ---- row softmax in place over bf16 S, ncol = 8192 (256 thr x 32 elems) ----
__global__ __launch_bounds__(256) void softmax_kernel(unsigned short* __restrict__ S,
                                                      int ncol) {
  const int t = threadIdx.x;
  unsigned short* rp = S + (size_t)blockIdx.x * ncol;
  ushort8* rv = (ushort8*)rp;
  float f[32];
#pragma unroll
  for (int c = 0; c < 4; ++c) {
    ushort8 v = rv[c * 256 + t];
#pragma unroll
    for (int j = 0; j < 8; ++j) f[c * 8 + j] = bf2f(v[j]);
  }
  float m = -1e30f;
#pragma unroll
  for (int i = 0; i < 32; ++i) m = fmaxf(m, f[i]);
#pragma unroll
  for (int o = 32; o; o >>= 1) m = fmaxf(m, __shfl_xor(m, o));
  __shared__ float red[8];
  if ((t & 63) == 0) red[t >> 6] = m;
  __syncthreads();
  m = fmaxf(fmaxf(red[0], red[1]), fmaxf(red[2], red[3]));

  float s = 0.0f;
#pragma unroll
  for (int i = 0; i < 32; ++i) {
    f[i] = __expf(f[i] - m);
    s += f[i];
  }
#pragma unroll
  for (int o = 32; o; o >>= 1) s += __shfl_xor(s, o);
  if ((t & 63) == 0) red[4 + (t >> 6)] = s;
  __syncthreads();
  s = red[4] + red[5] + red[6] + red[7];
  float inv = 1.0f / s;
#pragma unroll
  for (int c = 0; c < 4; ++c) {
    ushort8 v;
#pragma unroll
    for (int j = 0; j < 8; ++j) v[j] = f2bf(f[c * 8 + j] * inv);
    rv[c * 256 + t] = v;
  }
}

// ---- 64x64 tiled transpose: out[C][R] = in[R][C] (bf16) ----
__global__ __launch_bounds__(256) void transpose_kernel(
    const unsigned short* __restrict__ in, unsigned short* __restrict__ out,
    int R, int Ccols) {
  __shared__ unsigned short tile[64][65];
  const int tx = threadIdx.x & 63, ty = threadIdx.x >> 6;
  const int r0 = blockIdx.y * 64, c0 = blockIdx.x * 64;
#pragma unroll
  for (int i = 0; i < 16; ++i) {
    int r = ty * 16 + i;
    tile[r][tx] = in[(size_t)(r0 + r) * Ccols + c0 + tx];
  }
  __syncthreads();
#pragma unroll
  for (int i = 0; i < 16; ++i) {
    int r = ty * 16 + i;
    out[(size_t)(c0 + r) * R + r0 + tx] = tile[tx][r];
  }
}

extern "C" void kernel_launch(void* const* d_in, const int* in_sizes, int n_in,
                              void* d_out, int out_size, void* d_ws, size_t ws_size,
                              hipStream_t stream) {
  (void)in_sizes; (void)n_in; (void)out_size; (void)ws_size;
  const int N = 8192, D = 1024;
  const float* x  = (const float*)d_in[0];
  const float* Wq = (const float*)d_in[1];
  const float* Wk = (const float*)d_in[2];
  const float* Wv = (const float*)d_in[3];
  float* out = (float*)d_out;

  char* ws = (char*)d_ws;
  size_t off = 0;
  auto alloc = [&](size_t bytes) { char* p = ws + off; off += bytes; return p; };
  unsigned short* xh  = (unsigned short*)alloc((size_t)N * D * 2);  // 16.8 MB
  unsigned short* Wqh = (unsigned short*)alloc((size_t)D * D * 2);  // 2 MB
  unsigned short* Wkh = (unsigned short*)alloc((size_t)D * D * 2);
  unsigned short* Wvh = (unsigned short*)alloc((size_t)D * D * 2);
  unsigned short* Qh  = (unsigned short*)alloc((size_t)N * D * 2);  // 16.8 MB
  unsigned short* Kh  = (unsigned short*)alloc((size_t)N * D * 2);
  unsigned short* Vh  = (unsigned short*)alloc((size_t)N * D * 2);
  unsigned short* S   = (unsigned short*)alloc((size_t)N * N * 2);  // 134.2 MB
  unsigned short* Vth = xh;            // xh dead after QKV
  float* Pbuf = (float*)Qh;            // Qh+Kh (33.6 MB) dead after S-GEMM

  // casts
  cast_kernel<<<(N * D / 8) / 256, 256, 0, stream>>>(x, xh, N * D / 8);
  cast_kernel<<<(D * D / 8) / 256, 256, 0, stream>>>(Wq, Wqh, D * D / 8);
  cast_kernel<<<(D * D / 8) / 256, 256, 0, stream>>>(Wk, Wkh, D * D / 8);
  cast_kernel<<<(D * D / 8) / 256, 256, 0, stream>>>(Wv, Wvh, D * D / 8);

  // Q,K,V = x @ W^T  (fused over z)
  gemm_qkv_kernel<<<dim3(8, 64, 3), 256, 0, stream>>>(xh, Wqh, Wkh, Wvh,
                                                      Qh, Kh, Vh);

  // S = Q @ K^T * (1/32)
  gemm_s_kernel<<<dim3(64, 64), 256, 0, stream>>>(Qh, Kh, S);

  // softmax rows (in place)
  softmax_kernel<<<N, 256, 0, stream>>>(S, N);

  // Vt = V^T  [1024,8192]
  transpose_kernel<<<dim3(D / 64, N / 64), 256, 0, stream>>>(Vh, Vth, N, D);

  // out = P @ Vt^T  (split-K x2, 1024 blocks = 4/CU)
  gemm_pv_kernel<<<dim3(8, 64, 2), 256, 0, stream>>>(S, Vth, out, Pbuf);

  // out += partial
  add_kernel<<<(N * D / 4) / 256, 256, 0, stream>>>(out, Pbuf, N * D / 4);
}